// Round 1
// baseline (383.380 us; speedup 1.0000x reference)
//
#include <hip/hip_runtime.h>

#define NN 50000
#define EE 800000
#define IND 128
#define EDD 32
#define ODD 16
#define NH 4
#define HD 64
#define NEG_SLOPE 0.2f
#define NBLK ((NN + 255) / 256)   // 196 scan blocks

typedef float  f32x4 __attribute__((ext_vector_type(4)));
typedef int    i32x2 __attribute__((ext_vector_type(2)));
typedef _Float16 f16x8 __attribute__((ext_vector_type(8)));

// ---------------- init+prep fused: deg=0; Wt transpose; w_ee fold ----------
__global__ __launch_bounds__(256)
void k_init_prep(int* __restrict__ deg, const float* __restrict__ W_fc,
                 const float* __restrict__ W_edge, const float* __restrict__ attn_e,
                 float* __restrict__ Wt, float* __restrict__ w_ee) {
    int i = blockIdx.x * 256 + threadIdx.x;
    if (i < NN) deg[i] = 0;
    if (i < HD * IND) {
        int k = i >> 6, j = i & 63;
        Wt[i] = W_fc[j * IND + k];
    }
    if (i < NH * EDD) {
        int h = i >> 5, k = i & 31;
        float s = 0.f;
        for (int d = 0; d < ODD; ++d)
            s += W_edge[(h * ODD + d) * EDD + k] * attn_e[h * ODD + d];
        w_ee[i] = s;
    }
}

// ------- node projection: gridDim.y=2 halves (block-uniform -> s_load weights)
// ------- full feat row prefetched (nontemporal: pure stream); fp16 output rows
__global__ __launch_bounds__(256)
void k_node(const float* __restrict__ feat, const float* __restrict__ Wt,
            const float* __restrict__ attn_h, const float* __restrict__ attn_t,
            _Float16* __restrict__ feat_h, float2* __restrict__ eh2,
            float2* __restrict__ et2) {
    int n = blockIdx.x * 256 + threadIdx.x;
    int hf = blockIdx.y;                    // block-uniform -> scalar weight loads
    if (n >= NN) return;
    const int jbase = hf * 32;
    f32x4 row[32];
    const f32x4* fr4 = (const f32x4*)(feat + (long)n * IND);
#pragma unroll
    for (int q = 0; q < 32; ++q) row[q] = __builtin_nontemporal_load(fr4 + q);
    asm volatile("" ::: "memory");          // keep all 32 loads hoisted
    float acc[32];
#pragma unroll
    for (int j = 0; j < 32; ++j) acc[j] = 0.f;
#pragma unroll
    for (int k0 = 0; k0 < 32; ++k0) {
        float f[4] = {row[k0][0], row[k0][1], row[k0][2], row[k0][3]};
#pragma unroll
        for (int kk = 0; kk < 4; ++kk) {
            const float* w = Wt + (k0 * 4 + kk) * HD + jbase;  // wave-uniform
#pragma unroll
            for (int j = 0; j < 32; ++j) acc[j] += f[kk] * w[j];
        }
    }
    // fp16 pack: 32 halves = 4 x 16B stores
    f16x8* d8 = (f16x8*)(feat_h + (long)n * HD + jbase);
#pragma unroll
    for (int q = 0; q < 4; ++q) {
        f16x8 v;
#pragma unroll
        for (int j = 0; j < 8; ++j) v[j] = (_Float16)acc[q * 8 + j];
        d8[q] = v;
    }
    float sh[2], st[2];
#pragma unroll
    for (int hh = 0; hh < 2; ++hh) {
        sh[hh] = 0.f; st[hh] = 0.f;
        int hg = hf * 2 + hh;
#pragma unroll
        for (int d = 0; d < ODD; ++d) {
            float av = acc[hh * ODD + d];
            sh[hh] += av * attn_h[hg * ODD + d];
            st[hh] += av * attn_t[hg * ODD + d];
        }
    }
    eh2[n * 2 + hf] = make_float2(sh[0], sh[1]);
    et2[n * 2 + hf] = make_float2(st[0], st[1]);
}

// ---------------- histogram of dst + per-edge rank --------------------------
__global__ __launch_bounds__(256)
void k_hist(const int* __restrict__ dst, int* __restrict__ deg, int* __restrict__ rank) {
    int e = blockIdx.x * 256 + threadIdx.x;
    if (e < EE) {
        int d = __builtin_nontemporal_load(dst + e);
        rank[e] = atomicAdd(&deg[d], 1);
    }
}

// ---------------- two-level exclusive scan of deg -> offs -------------------
__global__ __launch_bounds__(256)
void k_scan1(const int* __restrict__ deg, int* __restrict__ offs, int* __restrict__ part) {
    __shared__ int s[256];
    int t = threadIdx.x, i = blockIdx.x * 256 + t;
    int v = (i < NN) ? deg[i] : 0;
    s[t] = v;
    __syncthreads();
#pragma unroll
    for (int o = 1; o < 256; o <<= 1) {
        int u = (t >= o) ? s[t - o] : 0;
        __syncthreads();
        if (t >= o) s[t] += u;
        __syncthreads();
    }
    if (i < NN) offs[i] = s[t] - v;
    if (t == 255) part[blockIdx.x] = s[255];
}

__global__ __launch_bounds__(256)
void k_scan2(int* __restrict__ part) {
    __shared__ int s[256];
    int t = threadIdx.x;
    int v = (t < NBLK) ? part[t] : 0;
    s[t] = v;
    __syncthreads();
#pragma unroll
    for (int o = 1; o < 256; o <<= 1) {
        int u = (t >= o) ? s[t - o] : 0;
        __syncthreads();
        if (t >= o) s[t] += u;
        __syncthreads();
    }
    if (t < NBLK) part[t] = s[t] - v;
}

__global__ __launch_bounds__(256)
void k_scan3(int* __restrict__ offs, const int* __restrict__ part) {
    int i = blockIdx.x * 256 + threadIdx.x;
    if (i < NN) offs[i] += part[i >> 8];
}

// ------- edge pass (2 edges/thread): FULL logit + exp here ------------------
// a = exp(leakyrelu(ea@w_ee + eh[src] + et[dst])); scatter dst-ordered records
// (asrc, a4) to offs[dst]+rank. eh4/et4/offs are L2-resident (0.8-1.6 MB).
// No max-shift needed: logits are 0.1-scale (|x| < ~4).
__global__ __launch_bounds__(256)
void k_edge(const float* __restrict__ edge_attr, const int* __restrict__ dst,
            const int* __restrict__ src, const float* __restrict__ w_ee,
            const int* __restrict__ offs, const int* __restrict__ rank,
            const float4* __restrict__ eh4, const float4* __restrict__ et4,
            float4* __restrict__ a4, int* __restrict__ asrc) {
    int t = blockIdx.x * 256 + threadIdx.x;
    int e0 = t * 2;
    if (e0 >= EE) return;
    i32x2 d2 = __builtin_nontemporal_load((const i32x2*)(dst + e0));
    i32x2 r2 = __builtin_nontemporal_load((const i32x2*)(rank + e0));
    i32x2 s2 = __builtin_nontemporal_load((const i32x2*)(src + e0));
    int o0 = offs[d2[0]], o1 = offs[d2[1]];
    const f32x4* ea = (const f32x4*)(edge_attr + (long)e0 * EDD);
    f32x4 r[16];
#pragma unroll
    for (int c = 0; c < 16; ++c) r[c] = __builtin_nontemporal_load(ea + c);
    asm volatile("" ::: "memory");
    float4 eh0 = eh4[s2[0]], eh1 = eh4[s2[1]];
    float4 et0 = et4[d2[0]], et1 = et4[d2[1]];
    float he0[4] = {eh0.x + et0.x, eh0.y + et0.y, eh0.z + et0.z, eh0.w + et0.w};
    float he1[4] = {eh1.x + et1.x, eh1.y + et1.y, eh1.z + et1.z, eh1.w + et1.w};
    const float* f0 = (const float*)&r[0];
    const float* f1 = (const float*)&r[8];
    float a0[NH], a1[NH];
#pragma unroll
    for (int h = 0; h < NH; ++h) {
        float a = 0.f, b = 0.f;
#pragma unroll
        for (int k = 0; k < EDD; ++k) {
            float w = w_ee[h * EDD + k];    // uniform -> s_load
            a += f0[k] * w;
            b += f1[k] * w;
        }
        a += he0[h]; b += he1[h];
        a = a > 0.f ? a : NEG_SLOPE * a;
        b = b > 0.f ? b : NEG_SLOPE * b;
        a0[h] = __expf(a);
        a1[h] = __expf(b);
    }
    int p0 = o0 + r2[0], p1 = o1 + r2[1];
    a4[p0] = make_float4(a0[0], a0[1], a0[2], a0[3]);   // 16B aligned scatter
    a4[p1] = make_float4(a1[0], a1[1], a1[2], a1[3]);
    asrc[p0] = s2[0];
    asrc[p1] = s2[1];
}

// ------- per-dst reduce: coalesced record loads + fp16 row gather -----------
// only remaining random traffic: feat_h rows (128B each, 6.4MB array -> good L2 hit)
__global__ __launch_bounds__(256)
void k_reduce(const int* __restrict__ offs, const int* __restrict__ deg,
              const float* __restrict__ a_f, const int* __restrict__ asrc,
              const _Float16* __restrict__ feat_h, const float* __restrict__ bias,
              float* __restrict__ out) {
    int wid = (blockIdx.x * 256 + threadIdx.x) >> 6;   // one wave per dst node
    int lane = threadIdx.x & 63;
    if (wid >= NN) return;
    int start = __builtin_amdgcn_readfirstlane(offs[wid]);
    int dn    = __builtin_amdgcn_readfirstlane(deg[wid]);
    int h = lane >> 4;          // head of this lane
    int q = lane & 15;          // edge slot within chunk
    float acc = 0.f, l = 0.f;

    for (int c0 = 0; c0 < dn; c0 += 16) {
        int rem = dn - c0; if (rem > 16) rem = 16;
        int qq = (q < rem) ? q : (rem - 1);            // clamp: stay in-bounds
        int pos = start + c0 + qq;
        int   s_q = asrc[pos];                         // coalesced record load
        float a_q = a_f[(long)pos * 4 + h];            // coalesced (256B/wave)
        if (q >= rem) a_q = 0.f;
        float f[16];
#pragma unroll
        for (int i = 0; i < 16; ++i) {
            int si = __shfl(s_q, i);                   // edge i's src (quad 0)
            f[i] = (float)feat_h[(long)si * HD + lane]; // coalesced 128B row gather
        }
#pragma unroll
        for (int i = 0; i < 16; ++i) {
            float ai = __shfl(a_q, (lane & 48) + i);   // edge i, this lane's head
            l += ai;
            acc += ai * f[i];
        }
    }
    float res = (l > 0.f) ? acc / l : 0.f;
    __builtin_nontemporal_store(res + bias[lane], &out[(long)wid * HD + lane]);
}

extern "C" void kernel_launch(void* const* d_in, const int* in_sizes, int n_in,
                              void* d_out, int out_size, void* d_ws, size_t ws_size,
                              hipStream_t stream) {
    const float* feat      = (const float*)d_in[0];
    const float* edge_attr = (const float*)d_in[1];
    const int*   src       = (const int*)d_in[2];
    const int*   dst       = (const int*)d_in[3];
    const float* W_fc      = (const float*)d_in[4];
    const float* W_edge    = (const float*)d_in[5];
    const float* attn_h    = (const float*)d_in[6];
    const float* attn_t    = (const float*)d_in[7];
    const float* attn_e    = (const float*)d_in[8];
    const float* bias      = (const float*)d_in[9];
    float* out             = (float*)d_out;

    float* ws        = (float*)d_ws;
    float4* a4       = (float4*)ws;                    // E*4 floats (12.8 MB)
    float4* eh4      = a4 + EE;                        // N*4
    float4* et4      = eh4 + NN;                       // N*4
    _Float16* feat_h = (_Float16*)(et4 + NN);          // N*64 halves (6.4 MB)
    float*  Wt       = (float*)(feat_h + (long)NN * HD); // 8192
    float*  w_ee     = Wt + HD * IND;                  // 128
    int*    asrc     = (int*)(w_ee + NH * EDD);        // E
    int*    rank     = asrc + EE;                      // E
    int*    deg      = rank + EE;                      // N
    int*    offs     = deg + NN;                       // N
    int*    part     = offs + NN;                      // NBLK
    // total ~ 29 MB of d_ws

    k_init_prep<<<NBLK, 256, 0, stream>>>(deg, W_fc, W_edge, attn_e, Wt, w_ee);
    dim3 ngrid(NBLK, 2);
    k_node<<<ngrid, 256, 0, stream>>>(feat, Wt, attn_h, attn_t, feat_h,
                                      (float2*)eh4, (float2*)et4);
    k_hist<<<(EE + 255) / 256, 256, 0, stream>>>(dst, deg, rank);
    k_scan1<<<NBLK, 256, 0, stream>>>(deg, offs, part);
    k_scan2<<<1, 256, 0, stream>>>(part);
    k_scan3<<<NBLK, 256, 0, stream>>>(offs, part);
    k_edge<<<(EE / 2 + 255) / 256, 256, 0, stream>>>(edge_attr, dst, src, w_ee,
                                                     offs, rank, eh4, et4, a4, asrc);
    k_reduce<<<(NN * 64 + 255) / 256, 256, 0, stream>>>(offs, deg, (const float*)a4,
                                                        asrc, feat_h, bias, out);
}